// Round 6
// baseline (97.382 us; speedup 1.0000x reference)
//
#include <hip/hip_runtime.h>
#include <hip/hip_bf16.h>

#define BBATCH 16
#define NPTS   4096
#define NTOTAL (BBATCH*NPTS)            /* 65536 points per side */
#define ROWS_PER_BLOCK 128              /* 4 waves x 32 rows */
#define NCHUNKS (NPTS/ROWS_PER_BLOCK)   /* 32 n-chunks per batch */
#define MCHUNK 512                      /* m points staged in LDS per round */
#define NMCHUNKS (NPTS/MCHUNK)          /* 8 */
#define TILES (MCHUNK/32)               /* 16 MFMA col-tiles per chunk */

typedef unsigned int  uint_t;
typedef unsigned short ushort_t;
typedef __attribute__((ext_vector_type(8)))  short bf16x8;
typedef __attribute__((ext_vector_type(16))) float f32x16;

__device__ __forceinline__ ushort_t bfh(float v) {
  union { __hip_bfloat16 h; ushort_t u; } c; c.h = __float2bfloat16(v); return c.u;
}
__device__ __forceinline__ float bff(ushort_t u) {
  union { ushort_t u; __hip_bfloat16 h; } c; c.u = u; return __bfloat162float(c.h);
}
__device__ __forceinline__ float min3f(float a, float b, float c) {
  return fminf(fminf(a, b), c);   // clang fuses to v_min3_f32
}
// 16-value min via min3 tree: 8 ops instead of 15 pairwise
__device__ __forceinline__ float tree16(const f32x16& D) {
  float a = min3f(D[0],  D[1],  D[2]);
  float b = min3f(D[3],  D[4],  D[5]);
  float c = min3f(D[6],  D[7],  D[8]);
  float d = min3f(D[9],  D[10], D[11]);
  float e = min3f(D[12], D[13], D[14]);
  float f = min3f(a, b, c);
  float g = min3f(d, e, D[15]);
  return fminf(f, g);
}

// ---------------------------------------------------------------------------
// prep: build packed K=16 bf16 records so one mfma_32x32x16_bf16 yields full
// squared distances:  dot(A_n, B_m) = sx + sy - 2 x.y  (13 used slots)
//   A = [xh0..2, xl0..2, xh0..2, sxh, sxl, 1, 1, 0,0,0]
//   B = [zh0..2, zh0..2, zl0..2, 1, 1, syh, syl, 0,0,0],  z = -2*(y @ T)
// ---------------------------------------------------------------------------
__global__ __launch_bounds__(256) void prep(
    const float* __restrict__ Xv, const float* __restrict__ Yv,
    const float* __restrict__ Tm,
    ushort_t* __restrict__ Apack, ushort_t* __restrict__ Bpack,
    float* __restrict__ out)
{
  int idx = blockIdx.x * 256 + threadIdx.x;
  if (idx == 0) out[0] = 0.f;

  union { ushort_t r[16]; uint4 q[2]; } u;
  const ushort_t ONE = 0x3F80;

  if (idx < NTOTAL) {
    float x0 = Xv[idx*3], x1 = Xv[idx*3+1], x2 = Xv[idx*3+2];
    float sx = x0*x0 + x1*x1 + x2*x2;
    ushort_t h0=bfh(x0), h1=bfh(x1), h2=bfh(x2);
    ushort_t l0=bfh(x0-bff(h0)), l1=bfh(x1-bff(h1)), l2=bfh(x2-bff(h2));
    ushort_t sh=bfh(sx), sl=bfh(sx-bff(sh));
    u.r[0]=h0; u.r[1]=h1; u.r[2]=h2;  u.r[3]=l0; u.r[4]=l1; u.r[5]=l2;
    u.r[6]=h0; u.r[7]=h1; u.r[8]=h2;  u.r[9]=sh; u.r[10]=sl; u.r[11]=ONE; u.r[12]=ONE;
    u.r[13]=0; u.r[14]=0; u.r[15]=0;
    uint4* dst = (uint4*)(Apack + (size_t)idx*16);
    dst[0]=u.q[0]; dst[1]=u.q[1];
  } else {
    int j = idx - NTOTAL;
    int b = j >> 12;
    const float* T = Tm + b*16;
    float y0 = Yv[j*3], y1 = Yv[j*3+1], y2 = Yv[j*3+2];
    // row-vector transform; T[:,3] == [0,0,0,1]^T so w == 1 exactly
    float t0 = y0*T[0] + y1*T[4] + y2*T[8]  + T[12];
    float t1 = y0*T[1] + y1*T[5] + y2*T[9]  + T[13];
    float t2 = y0*T[2] + y1*T[6] + y2*T[10] + T[14];
    float sy = t0*t0 + t1*t1 + t2*t2;
    float z0 = -2.f*t0, z1 = -2.f*t1, z2 = -2.f*t2;
    ushort_t h0=bfh(z0), h1=bfh(z1), h2=bfh(z2);
    ushort_t l0=bfh(z0-bff(h0)), l1=bfh(z1-bff(h1)), l2=bfh(z2-bff(h2));
    ushort_t sh=bfh(sy), sl=bfh(sy-bff(sh));
    u.r[0]=h0; u.r[1]=h1; u.r[2]=h2;  u.r[3]=h0; u.r[4]=h1; u.r[5]=h2;
    u.r[6]=l0; u.r[7]=l1; u.r[8]=l2;  u.r[9]=ONE; u.r[10]=ONE; u.r[11]=sh; u.r[12]=sl;
    u.r[13]=0; u.r[14]=0; u.r[15]=0;
    uint4* dst = (uint4*)(Bpack + (size_t)j*16);
    dst[0]=u.q[0]; dst[1]=u.q[1];
  }
}

// ---------------------------------------------------------------------------
// chamfer_mfma: grid = 16 b x 32 n-chunks. Block = 4 waves x 32 x-rows.
// Tile-PAIRED inner loop: 2 mfma per iter; row-min via v_min3 (16 ops/2048
// pairs), col-min via 8-op min3 tree per tile + LDS atomicMin (kh halves
// share an address -> free 2-way combine). Per-block col-min slice stored
// with plain coalesced writes (NO global atomics); row-mins finalized by
// butterfly + block sum + one atomicAdd.
// D layout (m74/m101): col = lane&31 = B free index; rows vary only with
// reg index and lane>>5, so the 5-step butterfly over lane bits 0..4 is the
// full row reduction within each half.
// ---------------------------------------------------------------------------
__global__ __launch_bounds__(256) void chamfer_mfma(
    const ushort_t* __restrict__ Apack, const ushort_t* __restrict__ Bpack,
    uint_t* __restrict__ colminP, float* __restrict__ out)
{
  __shared__ uint4 Blo[MCHUNK];      // k0..7 halves  (8 KB)
  __shared__ uint4 Bhi[MCHUNK];      // k8..15 halves (8 KB)
  __shared__ uint_t colmin_s[NPTS];  // 16 KB
  __shared__ float blocksum;

  int tid = threadIdx.x, lane = tid & 63, wid = tid >> 6;
  int b = blockIdx.x / NCHUNKS;
  int nchunk = blockIdx.x % NCHUNKS;

  for (int i = tid; i < NPTS; i += 256) colmin_s[i] = 0x7F7F7F7Fu;
  if (tid == 0) blocksum = 0.f;

  int kh = lane >> 5;
  int row = nchunk * ROWS_PER_BLOCK + wid * 32 + (lane & 31);
  bf16x8 afrag = *((const bf16x8*)Apack + ((size_t)b * NPTS + row) * 2 + kh);

  float rm[16];
#pragma unroll
  for (int i = 0; i < 16; i++) rm[i] = 3e38f;

  const bf16x8* bbase = kh ? (const bf16x8*)Bhi : (const bf16x8*)Blo;

  for (int ch = 0; ch < NMCHUNKS; ++ch) {
    __syncthreads();
    const uint4* src = (const uint4*)(Bpack + ((size_t)b * NPTS + ch * MCHUNK) * 16);
    for (int s = tid; s < MCHUNK; s += 256) {
      Blo[s] = src[2*s];
      Bhi[s] = src[2*s+1];
    }
    __syncthreads();

#pragma unroll
    for (int tp = 0; tp < TILES/2; ++tp) {
      int ml0 = (tp * 2) * 32 + (lane & 31);
      bf16x8 b0 = bbase[ml0];
      bf16x8 b1 = bbase[ml0 + 32];
      f32x16 z = {};
      f32x16 D0 = __builtin_amdgcn_mfma_f32_32x32x16_bf16(afrag, b0, z, 0, 0, 0);
      f32x16 D1 = __builtin_amdgcn_mfma_f32_32x32x16_bf16(afrag, b1, z, 0, 0, 0);
#pragma unroll
      for (int i = 0; i < 16; i++) rm[i] = min3f(rm[i], D0[i], D1[i]);
      float c0 = tree16(D0);
      float c1 = tree16(D1);
      atomicMin(&colmin_s[ch * MCHUNK + ml0],      __float_as_uint(fmaxf(c0, 0.f)));
      atomicMin(&colmin_s[ch * MCHUNK + ml0 + 32], __float_as_uint(fmaxf(c1, 0.f)));
    }
  }

  // finalize row-mins: butterfly min over lane bits 0..4 (columns)
#pragma unroll
  for (int s = 1; s <= 16; s <<= 1) {
#pragma unroll
    for (int i = 0; i < 16; i++) rm[i] = fminf(rm[i], __shfl_xor(rm[i], s, 64));
  }
  float rs = 0.f;
#pragma unroll
  for (int i = 0; i < 16; i++) rs += fmaxf(rm[i], 0.f);
  if ((lane & 31) == 0) atomicAdd(&blocksum, rs);   // lanes 0,32 = the two row-halves
  __syncthreads();
  if (tid == 0) atomicAdd(out, blocksum);

  // flush this block's col-min slice (plain coalesced stores, no atomics)
  uint_t* dst = colminP + ((size_t)(b * NCHUNKS + nchunk) << 12);
  for (int i = tid; i < NPTS; i += 256) dst[i] = colmin_s[i];
}

// ---------------------------------------------------------------------------
// colreduce: per (b,m), min over the 32 n-chunk slices (already clamped >=0),
// sum everything into out.
// ---------------------------------------------------------------------------
__global__ __launch_bounds__(256) void colreduce(
    const uint_t* __restrict__ colminP, float* __restrict__ out)
{
  __shared__ float wsum[4];
  int idx = blockIdx.x * 256 + threadIdx.x;     // 65536 = one per (b,m)
  int b = idx >> 12, m = idx & (NPTS - 1);
  const uint_t* src = colminP + ((size_t)(b * NCHUNKS) << 12) + m;
  float v = 3e38f;
#pragma unroll
  for (int nc = 0; nc < NCHUNKS; ++nc)
    v = fminf(v, __uint_as_float(src[(size_t)nc << 12]));

  float s = v;
#pragma unroll
  for (int o = 32; o > 0; o >>= 1) s += __shfl_down(s, o, 64);
  int wid = threadIdx.x >> 6, lane = threadIdx.x & 63;
  if (lane == 0) wsum[wid] = s;
  __syncthreads();
  if (threadIdx.x == 0) atomicAdd(out, wsum[0] + wsum[1] + wsum[2] + wsum[3]);
}

extern "C" void kernel_launch(void* const* d_in, const int* in_sizes, int n_in,
                              void* d_out, int out_size, void* d_ws, size_t ws_size,
                              hipStream_t stream) {
  const float* Xv = (const float*)d_in[0];   // [B,N,3]
  const float* Yv = (const float*)d_in[1];   // [B,M,3]
  const float* Tm = (const float*)d_in[2];   // [B,4,4]
  float* out = (float*)d_out;

  char* ws = (char*)d_ws;
  ushort_t* Apack   = (ushort_t*)ws;                          // 2 MB
  ushort_t* Bpack   = (ushort_t*)(ws + (size_t)2*1024*1024);  // 2 MB
  uint_t*   colminP = (uint_t*)  (ws + (size_t)4*1024*1024);  // 8 MB (16x32x4096 u32)

  prep<<<(2 * NTOTAL) / 256, 256, 0, stream>>>(Xv, Yv, Tm, Apack, Bpack, out);
  chamfer_mfma<<<BBATCH * NCHUNKS, 256, 0, stream>>>(Apack, Bpack, colminP, out);
  colreduce<<<NTOTAL / 256, 256, 0, stream>>>(colminP, out);
}

// Round 7
// 91.478 us; speedup vs baseline: 1.0645x; 1.0645x over previous
//
#include <hip/hip_runtime.h>
#include <hip/hip_bf16.h>

#define BBATCH 16
#define NPTS   4096
#define NTOTAL (BBATCH*NPTS)            /* 65536 points per side */
#define ROWS_PER_BLOCK 128              /* 4 waves x 32 rows */
#define NCHUNKS (NPTS/ROWS_PER_BLOCK)   /* 32 n-chunks per (dir,batch) */
#define MCHUNK 512                      /* db points staged in LDS per round */
#define NMCHUNKS (NPTS/MCHUNK)          /* 8 */
#define TILES (MCHUNK/32)               /* 16 MFMA col-tiles per chunk */

typedef unsigned int  uint_t;
typedef unsigned short ushort_t;
typedef __attribute__((ext_vector_type(8)))  short bf16x8;
typedef __attribute__((ext_vector_type(16))) float f32x16;

__device__ __forceinline__ ushort_t bfh(float v) {
  union { __hip_bfloat16 h; ushort_t u; } c; c.h = __float2bfloat16(v); return c.u;
}
__device__ __forceinline__ float bff(ushort_t u) {
  union { ushort_t u; __hip_bfloat16 h; } c; c.u = u; return __bfloat162float(c.h);
}
__device__ __forceinline__ float min3f(float a, float b, float c) {
  return fminf(fminf(a, b), c);   // clang fuses to v_min3_f32
}

// K=16 bf16 record formats (hi/lo split makes dot() f32-accurate):
//   A-record(p, s): [ph0..2, pl0..2, ph0..2, sh, sl, 1, 1, 0,0,0]
//   B-record(z, s): [zh0..2, zh0..2, zl0..2, 1, 1, sh, sl, 0,0,0],  z = -2*p
//   dot(A_n, B_m) = s_n + s_m - 2 p_n.p_m   (full squared distance)
__device__ __forceinline__ void emitA(ushort_t* dst, float p0, float p1, float p2, float s) {
  const ushort_t ONE = 0x3F80;
  union { ushort_t r[16]; uint4 q[2]; } u;
  ushort_t h0=bfh(p0), h1=bfh(p1), h2=bfh(p2);
  ushort_t l0=bfh(p0-bff(h0)), l1=bfh(p1-bff(h1)), l2=bfh(p2-bff(h2));
  ushort_t sh=bfh(s), sl=bfh(s-bff(sh));
  u.r[0]=h0; u.r[1]=h1; u.r[2]=h2;  u.r[3]=l0; u.r[4]=l1; u.r[5]=l2;
  u.r[6]=h0; u.r[7]=h1; u.r[8]=h2;  u.r[9]=sh; u.r[10]=sl; u.r[11]=ONE; u.r[12]=ONE;
  u.r[13]=0; u.r[14]=0; u.r[15]=0;
  uint4* d4 = (uint4*)dst; d4[0]=u.q[0]; d4[1]=u.q[1];
}
__device__ __forceinline__ void emitB(ushort_t* dst, float z0, float z1, float z2, float s) {
  const ushort_t ONE = 0x3F80;
  union { ushort_t r[16]; uint4 q[2]; } u;
  ushort_t h0=bfh(z0), h1=bfh(z1), h2=bfh(z2);
  ushort_t l0=bfh(z0-bff(h0)), l1=bfh(z1-bff(h1)), l2=bfh(z2-bff(h2));
  ushort_t sh=bfh(s), sl=bfh(s-bff(sh));
  u.r[0]=h0; u.r[1]=h1; u.r[2]=h2;  u.r[3]=h0; u.r[4]=h1; u.r[5]=h2;
  u.r[6]=l0; u.r[7]=l1; u.r[8]=l2;  u.r[9]=ONE; u.r[10]=ONE; u.r[11]=sh; u.r[12]=sl;
  u.r[13]=0; u.r[14]=0; u.r[15]=0;
  uint4* d4 = (uint4*)dst; d4[0]=u.q[0]; d4[1]=u.q[1];
}

// ---------------------------------------------------------------------------
// prep: each thread owns one point and emits BOTH its A-record and B-record.
//   X points  -> ApackX, BpackX;  transformed targets -> ApackT, BpackT.
// ---------------------------------------------------------------------------
__global__ __launch_bounds__(256) void prep(
    const float* __restrict__ Xv, const float* __restrict__ Yv,
    const float* __restrict__ Tm,
    ushort_t* __restrict__ ApackX, ushort_t* __restrict__ BpackX,
    ushort_t* __restrict__ ApackT, ushort_t* __restrict__ BpackT,
    float* __restrict__ out)
{
  int idx = blockIdx.x * 256 + threadIdx.x;
  if (idx == 0) out[0] = 0.f;

  if (idx < NTOTAL) {
    float x0 = Xv[idx*3], x1 = Xv[idx*3+1], x2 = Xv[idx*3+2];
    float sx = x0*x0 + x1*x1 + x2*x2;
    emitA(ApackX + (size_t)idx*16, x0, x1, x2, sx);
    emitB(BpackX + (size_t)idx*16, -2.f*x0, -2.f*x1, -2.f*x2, sx);
  } else {
    int j = idx - NTOTAL;
    int b = j >> 12;
    const float* T = Tm + b*16;
    float y0 = Yv[j*3], y1 = Yv[j*3+1], y2 = Yv[j*3+2];
    // row-vector transform; T[:,3] == [0,0,0,1]^T so w == 1 exactly
    float t0 = y0*T[0] + y1*T[4] + y2*T[8]  + T[12];
    float t1 = y0*T[1] + y1*T[5] + y2*T[9]  + T[13];
    float t2 = y0*T[2] + y1*T[6] + y2*T[10] + T[14];
    float sy = t0*t0 + t1*t1 + t2*t2;
    emitA(ApackT + (size_t)j*16, t0, t1, t2, sy);
    emitB(BpackT + (size_t)j*16, -2.f*t0, -2.f*t1, -2.f*t2, sy);
  }
}

// ---------------------------------------------------------------------------
// chamfer_rm: ROW-MIN ONLY, both directions via operand swap.
//   grid.x = 2*BBATCH*NCHUNKS (1024 blocks = 4/CU = 4 waves/SIMD).
//   z <  16: A = X rows, B = target cols   (X -> target NN distances)
//   z >= 16: A = target rows, B = X cols   (target -> X NN distances)
// Per tile-pair inner loop: 2 ds_read_b128 + 2 mfma_32x32x16_bf16 + 16 v_min3.
// No LDS atomics, no col-min state. Epilogue: 5-step lane butterfly (cols),
// clamp, per-lane sum, LDS blocksum, one atomicAdd(out) per block.
// D layout (m74/m101): col = lane&31 (B free idx), row = (i&3)+8*(i>>2)+4*kh.
// ---------------------------------------------------------------------------
__global__ __launch_bounds__(256, 4) void chamfer_rm(
    const ushort_t* __restrict__ ApackX, const ushort_t* __restrict__ BpackX,
    const ushort_t* __restrict__ ApackT, const ushort_t* __restrict__ BpackT,
    float* __restrict__ out)
{
  __shared__ uint4 Blo[MCHUNK];      // k0..7 halves  (8 KB)
  __shared__ uint4 Bhi[MCHUNK];      // k8..15 halves (8 KB)
  __shared__ float blocksum;

  int tid = threadIdx.x, lane = tid & 63, wid = tid >> 6;
  int zz = blockIdx.x / NCHUNKS;          // 0..31
  int nchunk = blockIdx.x % NCHUNKS;
  int b = zz & (BBATCH - 1);
  const ushort_t* Ap = (zz < BBATCH) ? ApackX : ApackT;
  const ushort_t* Bp = (zz < BBATCH) ? BpackT : BpackX;

  if (tid == 0) blocksum = 0.f;

  int kh = lane >> 5;
  int row = nchunk * ROWS_PER_BLOCK + wid * 32 + (lane & 31);
  bf16x8 afrag = *((const bf16x8*)Ap + ((size_t)b * NPTS + row) * 2 + kh);

  float rm[16];
#pragma unroll
  for (int i = 0; i < 16; i++) rm[i] = 3e38f;

  const bf16x8* bbase = kh ? (const bf16x8*)Bhi : (const bf16x8*)Blo;

  for (int ch = 0; ch < NMCHUNKS; ++ch) {
    __syncthreads();
    const uint4* src = (const uint4*)(Bp + ((size_t)b * NPTS + ch * MCHUNK) * 16);
    for (int s = tid; s < MCHUNK; s += 256) {
      Blo[s] = src[2*s];
      Bhi[s] = src[2*s+1];
    }
    __syncthreads();

#pragma unroll
    for (int tp = 0; tp < TILES/2; ++tp) {
      int ml0 = tp * 64 + (lane & 31);
      bf16x8 b0 = bbase[ml0];
      bf16x8 b1 = bbase[ml0 + 32];
      f32x16 zc = {};
      f32x16 D0 = __builtin_amdgcn_mfma_f32_32x32x16_bf16(afrag, b0, zc, 0, 0, 0);
      f32x16 D1 = __builtin_amdgcn_mfma_f32_32x32x16_bf16(afrag, b1, zc, 0, 0, 0);
#pragma unroll
      for (int i = 0; i < 16; i++) rm[i] = min3f(rm[i], D0[i], D1[i]);
    }
  }

  // butterfly min over lane bits 0..4 (the 32 cols of the final tiles)
#pragma unroll
  for (int s = 1; s <= 16; s <<= 1) {
#pragma unroll
    for (int i = 0; i < 16; i++) rm[i] = fminf(rm[i], __shfl_xor(rm[i], s, 64));
  }
  float rs = 0.f;
#pragma unroll
  for (int i = 0; i < 16; i++) rs += fmaxf(rm[i], 0.f);
  if ((lane & 31) == 0) atomicAdd(&blocksum, rs);   // lanes 0,32 = the two row-halves
  __syncthreads();
  if (tid == 0) atomicAdd(out, blocksum);
}

extern "C" void kernel_launch(void* const* d_in, const int* in_sizes, int n_in,
                              void* d_out, int out_size, void* d_ws, size_t ws_size,
                              hipStream_t stream) {
  const float* Xv = (const float*)d_in[0];   // [B,N,3]
  const float* Yv = (const float*)d_in[1];   // [B,M,3]
  const float* Tm = (const float*)d_in[2];   // [B,4,4]
  float* out = (float*)d_out;

  char* ws = (char*)d_ws;
  ushort_t* ApackX = (ushort_t*)(ws + (size_t)0*1024*1024);
  ushort_t* BpackX = (ushort_t*)(ws + (size_t)2*1024*1024);
  ushort_t* ApackT = (ushort_t*)(ws + (size_t)4*1024*1024);
  ushort_t* BpackT = (ushort_t*)(ws + (size_t)6*1024*1024);

  prep<<<(2 * NTOTAL) / 256, 256, 0, stream>>>(Xv, Yv, Tm, ApackX, BpackX, ApackT, BpackT, out);
  chamfer_rm<<<2 * BBATCH * NCHUNKS, 256, 0, stream>>>(ApackX, BpackX, ApackT, BpackT, out);
}